// Round 1
// baseline (1102.275 us; speedup 1.0000x reference)
//
#include <hip/hip_runtime.h>
#include <hip/hip_bf16.h>

#define N_NODES 100000
#define N_EDGES 1600000
#define NFEAT 128
#define NHID 64
#define NCLASS 40

// ---------------- degree / norm ----------------

__global__ void deg_kernel(const int* __restrict__ ei, const float* __restrict__ w,
                           float* __restrict__ deg) {
    int e = blockIdx.x * blockDim.x + threadIdx.x;
    if (e < N_EDGES) {
        int c = ei[N_EDGES + e];          // col = target
        atomicAdd(&deg[c], w[e]);
    }
}

__global__ void dinv_kernel(float* __restrict__ deg) {
    int n = blockIdx.x * blockDim.x + threadIdx.x;
    if (n < N_NODES) {
        // self-loop adds weight 1.0 -> deg always > 0
        deg[n] = rsqrtf(deg[n] + 1.0f);
    }
}

__global__ void norm_kernel(const int* __restrict__ ei, const float* __restrict__ w,
                            const float* __restrict__ dinv, float* __restrict__ norm) {
    int e = blockIdx.x * blockDim.x + threadIdx.x;
    if (e < N_EDGES) {
        int r = ei[e];
        int c = ei[N_EDGES + e];
        norm[e] = dinv[r] * w[e] * dinv[c];
    }
}

// ---------------- layer 1 ----------------

// h1[N, 64] = x[N, 128] @ W1[128, 64]
// block = 256 threads = 4 rows x 64 cols
__global__ void gemm1_kernel(const float* __restrict__ x, const float* __restrict__ W1,
                             float* __restrict__ h1) {
    int row = blockIdx.x * 4 + (threadIdx.x >> 6);
    int j = threadIdx.x & 63;
    if (row >= N_NODES) return;
    const float* xr = x + (size_t)row * NFEAT;
    float s = 0.0f;
#pragma unroll
    for (int k = 0; k < NFEAT; ++k) {
        s += xr[k] * W1[k * NHID + j];
    }
    h1[(size_t)row * NHID + j] = s;
}

// agg1[col] += norm[e] * h1[row]  — block = 4 edges x 64 feats
__global__ void scatter1_kernel(const int* __restrict__ ei, const float* __restrict__ norm,
                                const float* __restrict__ h1, float* __restrict__ agg1) {
    int idx = blockIdx.x * 256 + threadIdx.x;
    int e = idx >> 6;
    int f = idx & 63;
    if (e >= N_EDGES) return;
    int r = ei[e];
    int c = ei[N_EDGES + e];
    float nm = norm[e];
    float v = nm * h1[(size_t)r * NHID + f];
    atomicAdd(&agg1[(size_t)c * NHID + f], v);
}

// agg1 = relu(agg1 + dinv^2 * h1 + b1)   (self-loop folded in), in place
__global__ void final1_kernel(float* __restrict__ agg1, const float* __restrict__ h1,
                              const float* __restrict__ dinv, const float* __restrict__ b1) {
    int idx = blockIdx.x * 256 + threadIdx.x;
    if (idx >= N_NODES * NHID) return;
    int n = idx >> 6;
    int f = idx & 63;
    float di = dinv[n];
    float v = agg1[idx] + di * di * h1[idx] + b1[f];
    agg1[idx] = fmaxf(v, 0.0f);
}

// ---------------- layer 2 ----------------

// h2[N, 40] = agg1[N, 64] @ W2[64, 40]
__global__ void gemm2_kernel(const float* __restrict__ in, const float* __restrict__ W2,
                             float* __restrict__ h2) {
    int idx = blockIdx.x * blockDim.x + threadIdx.x;
    if (idx >= N_NODES * NCLASS) return;
    int n = idx / NCLASS;
    int f = idx - n * NCLASS;
    const float* a = in + (size_t)n * NHID;
    float s = 0.0f;
#pragma unroll
    for (int k = 0; k < NHID; ++k) {
        s += a[k] * W2[k * NCLASS + f];
    }
    h2[idx] = s;
}

// out[col] += norm[e] * h2[row]
__global__ void scatter2_kernel(const int* __restrict__ ei, const float* __restrict__ norm,
                                const float* __restrict__ h2, float* __restrict__ out) {
    int idx = blockIdx.x * blockDim.x + threadIdx.x;
    if (idx >= N_EDGES * NCLASS) return;
    int e = idx / NCLASS;
    int f = idx - e * NCLASS;
    int r = ei[e];
    int c = ei[N_EDGES + e];
    float v = norm[e] * h2[(size_t)r * NCLASS + f];
    atomicAdd(&out[c * NCLASS + f], v);
}

// out += dinv^2 * h2 + b2
__global__ void final2_kernel(float* __restrict__ out, const float* __restrict__ h2,
                              const float* __restrict__ dinv, const float* __restrict__ b2) {
    int idx = blockIdx.x * blockDim.x + threadIdx.x;
    if (idx >= N_NODES * NCLASS) return;
    int n = idx / NCLASS;
    int f = idx - n * NCLASS;
    float di = dinv[n];
    out[idx] += di * di * h2[idx] + b2[f];
}

// ---------------- launch ----------------

extern "C" void kernel_launch(void* const* d_in, const int* in_sizes, int n_in,
                              void* d_out, int out_size, void* d_ws, size_t ws_size,
                              hipStream_t stream) {
    const float* x  = (const float*)d_in[0];
    const int*   ei = (const int*)d_in[1];     // [2, E] int32
    const float* ew = (const float*)d_in[2];
    const float* W1 = (const float*)d_in[3];
    const float* b1 = (const float*)d_in[4];
    const float* W2 = (const float*)d_in[5];
    const float* b2 = (const float*)d_in[6];
    float* out = (float*)d_out;

    // workspace layout (floats)
    float* deg  = (float*)d_ws;                        // N (becomes dinv)
    float* norm = deg + 131072;                        // E
    float* h1   = norm + N_EDGES;                      // N*64
    float* agg1 = h1 + (size_t)N_NODES * NHID;         // N*64 (becomes relu output)
    float* h2   = agg1 + (size_t)N_NODES * NHID;       // N*40

    // zero accumulators
    hipMemsetAsync(deg, 0, (size_t)N_NODES * sizeof(float), stream);
    hipMemsetAsync(agg1, 0, (size_t)N_NODES * NHID * sizeof(float), stream);
    hipMemsetAsync(out, 0, (size_t)N_NODES * NCLASS * sizeof(float), stream);

    // degree + norm
    deg_kernel<<<(N_EDGES + 255) / 256, 256, 0, stream>>>(ei, ew, deg);
    dinv_kernel<<<(N_NODES + 255) / 256, 256, 0, stream>>>(deg);
    norm_kernel<<<(N_EDGES + 255) / 256, 256, 0, stream>>>(ei, ew, deg, norm);

    // layer 1
    gemm1_kernel<<<(N_NODES + 3) / 4, 256, 0, stream>>>(x, W1, h1);
    scatter1_kernel<<<(N_EDGES * 64 + 255) / 256, 256, 0, stream>>>(ei, norm, h1, agg1);
    final1_kernel<<<(N_NODES * NHID + 255) / 256, 256, 0, stream>>>(agg1, h1, deg, b1);

    // layer 2
    gemm2_kernel<<<(N_NODES * NCLASS + 255) / 256, 256, 0, stream>>>(agg1, W2, h2);
    scatter2_kernel<<<(N_EDGES * NCLASS + 255) / 256, 256, 0, stream>>>(ei, norm, h2, out);
    final2_kernel<<<(N_NODES * NCLASS + 255) / 256, 256, 0, stream>>>(out, h2, deg, b2);
}

// Round 2
// 865.403 us; speedup vs baseline: 1.2737x; 1.2737x over previous
//
#include <hip/hip_runtime.h>
#include <hip/hip_bf16.h>

#define N_NODES 100000
#define N_EDGES 1600000
#define NFEAT 128
#define NHID 64
#define NCLASS 40

#define SCAN_CHUNK 1024
#define NBLK ((N_NODES + SCAN_CHUNK - 1) / SCAN_CHUNK)   // 98

// ---------------- counting sort by destination ----------------

__global__ void hist_kernel(const int* __restrict__ ei, int* __restrict__ cnt) {
    int e = blockIdx.x * blockDim.x + threadIdx.x;
    if (e < N_EDGES) {
        atomicAdd(&cnt[ei[N_EDGES + e]], 1);
    }
}

// per-block sums of 1024-element chunks
__global__ void scan_reduce_kernel(const int* __restrict__ cnt, int* __restrict__ bsum) {
    __shared__ int s[256];
    int b = blockIdx.x, t = threadIdx.x;
    int base = b * SCAN_CHUNK + t * 4;
    int v = 0;
#pragma unroll
    for (int j = 0; j < 4; ++j) {
        int i = base + j;
        if (i < N_NODES) v += cnt[i];
    }
    s[t] = v;
    __syncthreads();
    for (int o = 128; o > 0; o >>= 1) {
        if (t < o) s[t] += s[t + o];
        __syncthreads();
    }
    if (t == 0) bsum[b] = s[0];
}

// exclusive scan of the 98 block sums (tiny, single block)
__global__ void scan_block_kernel(int* __restrict__ bsum) {
    __shared__ int s[NBLK];
    int t = threadIdx.x;
    if (t < NBLK) s[t] = bsum[t];
    __syncthreads();
    if (t == 0) {
        int acc = 0;
        for (int i = 0; i < NBLK; ++i) {
            int v = s[i];
            s[i] = acc;
            acc += v;
        }
    }
    __syncthreads();
    if (t < NBLK) bsum[t] = s[t];
}

// in-place: cnt -> exclusive prefix (off)
__global__ void scan_final_kernel(int* __restrict__ cnt, const int* __restrict__ bsum) {
    __shared__ int s[256];
    int b = blockIdx.x, t = threadIdx.x;
    int base = b * SCAN_CHUNK + t * 4;
    int v[4];
    int sum = 0;
#pragma unroll
    for (int j = 0; j < 4; ++j) {
        int i = base + j;
        v[j] = (i < N_NODES) ? cnt[i] : 0;
        sum += v[j];
    }
    s[t] = sum;
    __syncthreads();
    // Hillis-Steele inclusive scan over 256 thread sums
    for (int o = 1; o < 256; o <<= 1) {
        int add = (t >= o) ? s[t - o] : 0;
        __syncthreads();
        s[t] += add;
        __syncthreads();
    }
    int excl = s[t] - sum + bsum[b];
#pragma unroll
    for (int j = 0; j < 4; ++j) {
        int i = base + j;
        if (i < N_NODES) cnt[i] = excl;
        excl += v[j];
    }
}

// scatter edges into sorted-by-col order
__global__ void reorder_kernel(const int* __restrict__ ei, const float* __restrict__ w,
                               const int* __restrict__ off, int* __restrict__ cursor,
                               int* __restrict__ srow, float* __restrict__ sw) {
    int e = blockIdx.x * blockDim.x + threadIdx.x;
    if (e < N_EDGES) {
        int c = ei[N_EDGES + e];
        int pos = off[c] + atomicAdd(&cursor[c], 1);
        srow[pos] = ei[e];
        sw[pos] = w[e];
    }
}

// dinv[c] = rsqrt(sum_w_in_segment + 1)   (self-loop weight 1)
__global__ void dinv_kernel(const int* __restrict__ off, const float* __restrict__ sw,
                            float* __restrict__ dinv) {
    int c = blockIdx.x * blockDim.x + threadIdx.x;
    if (c >= N_NODES) return;
    int beg = off[c];
    int end = (c == N_NODES - 1) ? N_EDGES : off[c + 1];
    float s = 1.0f;
    for (int p = beg; p < end; ++p) s += sw[p];
    dinv[c] = rsqrtf(s);
}

// ---------------- layer 1 ----------------

// h1[N, 64] = x[N, 128] @ W1[128, 64]; block = 4 rows x 64 cols
__global__ void gemm1_kernel(const float* __restrict__ x, const float* __restrict__ W1,
                             float* __restrict__ h1) {
    int row = blockIdx.x * 4 + (threadIdx.x >> 6);
    int j = threadIdx.x & 63;
    if (row >= N_NODES) return;
    const float* xr = x + (size_t)row * NFEAT;
    float s = 0.0f;
#pragma unroll
    for (int k = 0; k < NFEAT; ++k) {
        s += xr[k] * W1[k * NHID + j];
    }
    h1[(size_t)row * NHID + j] = s;
}

// gather-aggregate + self-loop + bias + relu; one 64-lane wave per node
__global__ void gather1_kernel(const int* __restrict__ off, const int* __restrict__ srow,
                               const float* __restrict__ sw, const float* __restrict__ dinv,
                               const float* __restrict__ h1, const float* __restrict__ b1,
                               float* __restrict__ relu1) {
    int node = blockIdx.x * 4 + (threadIdx.x >> 6);
    int f = threadIdx.x & 63;
    if (node >= N_NODES) return;
    float dc = dinv[node];
    int beg = off[node];
    int end = (node == N_NODES - 1) ? N_EDGES : off[node + 1];
    float acc = b1[f] + dc * dc * h1[(size_t)node * NHID + f];
    for (int p = beg; p < end; ++p) {
        int r = srow[p];
        float coeff = dc * sw[p] * dinv[r];
        acc += coeff * h1[(size_t)r * NHID + f];
    }
    relu1[(size_t)node * NHID + f] = fmaxf(acc, 0.0f);
}

// ---------------- layer 2 ----------------

// h2[N, 40] = relu1[N, 64] @ W2[64, 40]
__global__ void gemm2_kernel(const float* __restrict__ in, const float* __restrict__ W2,
                             float* __restrict__ h2) {
    int idx = blockIdx.x * blockDim.x + threadIdx.x;
    if (idx >= N_NODES * NCLASS) return;
    int n = idx / NCLASS;
    int f = idx - n * NCLASS;
    const float* a = in + (size_t)n * NHID;
    float s = 0.0f;
#pragma unroll
    for (int k = 0; k < NHID; ++k) {
        s += a[k] * W2[k * NCLASS + f];
    }
    h2[idx] = s;
}

// gather-aggregate + self-loop + bias; one 64-lane wave per node, 40 active lanes
__global__ void gather2_kernel(const int* __restrict__ off, const int* __restrict__ srow,
                               const float* __restrict__ sw, const float* __restrict__ dinv,
                               const float* __restrict__ h2, const float* __restrict__ b2,
                               float* __restrict__ out) {
    int node = blockIdx.x * 4 + (threadIdx.x >> 6);
    int f = threadIdx.x & 63;
    if (node >= N_NODES) return;
    bool valid = (f < NCLASS);
    float dc = dinv[node];
    int beg = off[node];
    int end = (node == N_NODES - 1) ? N_EDGES : off[node + 1];
    float acc = 0.0f;
    if (valid) acc = b2[f] + dc * dc * h2[(size_t)node * NCLASS + f];
    for (int p = beg; p < end; ++p) {
        int r = srow[p];
        float coeff = dc * sw[p] * dinv[r];
        if (valid) acc += coeff * h2[(size_t)r * NCLASS + f];
    }
    if (valid) out[(size_t)node * NCLASS + f] = acc;
}

// ---------------- launch ----------------

extern "C" void kernel_launch(void* const* d_in, const int* in_sizes, int n_in,
                              void* d_out, int out_size, void* d_ws, size_t ws_size,
                              hipStream_t stream) {
    const float* x  = (const float*)d_in[0];
    const int*   ei = (const int*)d_in[1];     // [2, E]
    const float* ew = (const float*)d_in[2];
    const float* W1 = (const float*)d_in[3];
    const float* b1 = (const float*)d_in[4];
    const float* W2 = (const float*)d_in[5];
    const float* b2 = (const float*)d_in[6];
    float* out = (float*)d_out;

    // workspace layout
    int*   off    = (int*)d_ws;                        // N (exclusive prefix, in-place from counts)
    int*   cursor = off + 100352;                      // N
    int*   srow   = cursor + 100352;                   // E
    float* sw     = (float*)(srow + N_EDGES);          // E
    float* dinv   = sw + N_EDGES;                      // N
    int*   bsum   = (int*)(dinv + 100352);             // NBLK (98) pad 256
    float* h1     = (float*)(bsum + 256);              // N*64
    float* relu1  = h1 + (size_t)N_NODES * NHID;       // N*64
    float* h2     = relu1 + (size_t)N_NODES * NHID;    // N*40

    hipMemsetAsync(off, 0, (size_t)N_NODES * sizeof(int), stream);
    hipMemsetAsync(cursor, 0, (size_t)N_NODES * sizeof(int), stream);

    // CSR build
    hist_kernel<<<(N_EDGES + 255) / 256, 256, 0, stream>>>(ei, off);
    scan_reduce_kernel<<<NBLK, 256, 0, stream>>>(off, bsum);
    scan_block_kernel<<<1, 128, 0, stream>>>(bsum);
    scan_final_kernel<<<NBLK, 256, 0, stream>>>(off, bsum);
    reorder_kernel<<<(N_EDGES + 255) / 256, 256, 0, stream>>>(ei, ew, off, cursor, srow, sw);
    dinv_kernel<<<(N_NODES + 255) / 256, 256, 0, stream>>>(off, sw, dinv);

    // layer 1
    gemm1_kernel<<<(N_NODES + 3) / 4, 256, 0, stream>>>(x, W1, h1);
    gather1_kernel<<<(N_NODES + 3) / 4, 256, 0, stream>>>(off, srow, sw, dinv, h1, b1, relu1);

    // layer 2
    gemm2_kernel<<<(N_NODES * NCLASS + 255) / 256, 256, 0, stream>>>(relu1, W2, h2);
    gather2_kernel<<<(N_NODES + 3) / 4, 256, 0, stream>>>(off, srow, sw, dinv, h2, b2, out);
}